// Round 15
// baseline (2239.843 us; speedup 1.0000x reference)
//
#include <hip/hip_runtime.h>
#include <math.h>

typedef unsigned short u16;
typedef _Float16 f16;
typedef __attribute__((ext_vector_type(8))) _Float16 f16x8;
typedef __attribute__((ext_vector_type(4))) float floatx4;

#define NCELL 225
#define AST   136              // act stride in halves (272 B)
#define MAXF  31.75f
#define MAXM  (127.0f/((4.0f/16.0f)*3600.0f/256.0f))
#define DYN_LDS (2*NCELL*AST*2)   // 122,400 B: bufA | bufB

// f16 weight buffer layout (element offsets)
#define W_DCONV 0
#define W_C1    196608
#define W_R01   262144
#define W_R02   278528
#define W_FIN   294912
#define W_MAP   303104
#define W_TOT   303872

__device__ __forceinline__ float bfu(unsigned h){ union{unsigned i; float f;} v; v.i=h<<16; return v.f; }
__device__ __forceinline__ float silu_f(float x){ return x/(1.f+__expf(-x)); }
__device__ __forceinline__ float tanh_f(float z){ return 1.f - 2.f/(__expf(2.f*z)+1.f); }
__device__ __forceinline__ float ldp(const void* p, size_t i, int isf){
  return isf ? ((const float*)p)[i] : bfu(((const u16*)p)[i]);
}

__global__ __launch_bounds__(256) void k_prep(
    const void* __restrict__ dconv_w, const void* __restrict__ c1_w,
    const void* __restrict__ r0_w1,  const void* __restrict__ r0_w2,
    const void* __restrict__ fin_w,  const void* __restrict__ map_w,
    const void* __restrict__ x, f16* __restrict__ wbuf)
{
  __shared__ int sflag;
  if (threadIdx.x < 64) {
    unsigned v = ((const u16*)x)[2*threadIdx.x];
    unsigned long long m = __ballot(v > 0x4000u);
    if (threadIdx.x == 0) sflag = (__popcll(m) > 16) ? 1 : 0;
  }
  __syncthreads();
  const int isf = sflag;
  for (int i = blockIdx.x*256 + threadIdx.x; i < W_TOT; i += gridDim.x*256) {
    float v; int j = i;
    if (j < 196608)            v = ldp(dconv_w, j, isf);
    else if ((j -= 196608) < 65536) v = ldp(c1_w, j, isf);
    else if ((j -= 65536) < 16384)  v = ldp(r0_w1, j, isf);
    else if ((j -= 16384) < 16384)  v = ldp(r0_w2, j, isf);
    else if ((j -= 16384) < 8192)   v = ldp(fin_w, j, isf);
    else { j -= 8192;               v = ldp(map_w, j, isf); }
    wbuf[i] = (f16)v;
  }
}

// Ping-pong MFMA GEMM phase: reads S, writes D.
// 8 waves = 4 cell-groups (cg) x 2 channel-groups (ng); NT=4 (64 out-ch/wave).
// MODE 0: D = silu(acc+b). MODE 1: D = silu(acc+b) + D_old (residual read from D).
// One barrier at phase end.
template<int NTAPS, int MODE>
__device__ __forceinline__ void phase(
    const f16* __restrict__ S, f16* __restrict__ D, const f16* __restrict__ W,
    const void* __restrict__ Bv, size_t b0, int isf,
    int dr, int dc, int tid)
{
  const int lane = tid & 63, wave = tid >> 6;
  const int cg = wave >> 1, ng = wave & 1;
  const int quad = lane >> 4, lrow = lane & 15;
  const int chb = ng*64 + lrow;
  const int mt0 = cg * 4;

  floatx4 acc[4][4];
#pragma unroll
  for (int mi = 0; mi < 4; ++mi)
#pragma unroll
    for (int nt = 0; nt < 4; ++nt) { floatx4 z = {0.f,0.f,0.f,0.f}; acc[mi][nt] = z; }

#pragma unroll
  for (int t = 0; t < NTAPS; ++t) {
    const f16* ap[4]; bool vld[4];
#pragma unroll
    for (int mi = 0; mi < 4; ++mi) {
      const int mt = mt0 + mi;
      const int cell = mt*16 + lrow;
      const int r = cell/15, c = cell - r*15;
      const int off = (NTAPS == 3) ? (t - 1) : 0;
      const int rr = r + off*dr, cc = c + off*dc;
      vld[mi] = (mt < 15) & (cell < NCELL) & (rr >= 0) & (rr < 15) & (cc >= 0) & (cc < 15);
      ap[mi] = S + (vld[mi] ? (rr*15 + cc) : 0)*AST + quad*8;
    }
#pragma unroll
    for (int kb = 0; kb < 4; ++kb) {
      f16x8 Bf[4];
#pragma unroll
      for (int nt = 0; nt < 4; ++nt)
        Bf[nt] = *(const f16x8*)(W + (size_t)(t*128 + chb + nt*16)*128 + kb*32 + quad*8);
#pragma unroll
      for (int mi = 0; mi < 4; ++mi) {
        if (mt0 + mi < 15) {
          f16x8 a = *(const f16x8*)(ap[mi] + kb*32);
          if (!vld[mi]) { f16x8 z = {}; a = z; }
#pragma unroll
          for (int nt = 0; nt < 4; ++nt)
            acc[mi][nt] = __builtin_amdgcn_mfma_f32_16x16x32_f16(a, Bf[nt], acc[mi][nt], 0, 0, 0);
        }
      }
    }
  }

  float bn[4];
#pragma unroll
  for (int nt = 0; nt < 4; ++nt) bn[nt] = ldp(Bv, b0 + chb + nt*16, isf);

  // Epilogue: owner-only read-modify-write of D (safe: disjoint positions).
#pragma unroll
  for (int mi = 0; mi < 4; ++mi)
#pragma unroll
    for (int nt = 0; nt < 4; ++nt)
#pragma unroll
      for (int jp = 0; jp < 2; ++jp)
#pragma unroll
        for (int h = 0; h < 2; ++h) {
          const int oc = (mt0 + mi)*16 + quad*4 + jp*2 + h;
          if (oc < NCELL) {
            float v = silu_f(acc[mi][nt][jp*2+h] + bn[nt]);
            if (MODE == 1) v += (float)D[oc*AST + chb + nt*16];
            D[oc*AST + chb + nt*16] = (f16)v;
          }
        }
  __syncthreads();
}

__global__ __launch_bounds__(512, 2) void k_all(
    const void* __restrict__ x,
    const void* __restrict__ map_b,  const void* __restrict__ dconv_b,
    const void* __restrict__ c1_b,   const void* __restrict__ r0_b1,
    const void* __restrict__ r0_b2,  const void* __restrict__ fin_b,
    const void* __restrict__ prelu_w,
    const void* __restrict__ pdw_w,  const void* __restrict__ pdw_b,
    const void* __restrict__ ppw_w,
    const void* __restrict__ vl1_w,  const void* __restrict__ vl1_b,
    const void* __restrict__ vl2_w,  const void* __restrict__ vl2_b,
    const void* __restrict__ vlf_w,  const void* __restrict__ vlf_b,
    const void* __restrict__ pscale, const void* __restrict__ vscale,
    const f16* __restrict__ wbuf, float* __restrict__ out, int badflag)
{
  extern __shared__ __align__(16) char dyn[];
  f16* bufA = (f16*)dyn;                 // 61,200 B
  f16* bufB = bufA + NCELL*AST;          // 61,200 B
  __shared__ float xin[450];
  __shared__ float vred[512];
  __shared__ float vvA[32], vvB[32];
  __shared__ int sflag;

  const int b = blockIdx.x, tid = threadIdx.x;
  const int lane = tid & 63, wave = tid >> 6;
  const int cg = wave >> 1, ng = wave & 1;
  const int quad = lane >> 4, lrow = lane & 15;
  const int mt0 = cg * 4;

  if (tid < 64) {
    unsigned v = ((const u16*)x)[2*tid];
    unsigned long long m = __ballot(v > 0x4000u);
    if (tid == 0) sflag = (__popcll(m) > 16) ? 1 : 0;
  }
  __syncthreads();
  const int isf = sflag;

  for (int i = tid; i < 450; i += 512)
    xin[i] = ldp(x, (size_t)b*450 + i, isf);

  float facc[4][2][2][2];  // fin accumulator: [mi][nt][jp][h], ch = ng*32+nt*16+lrow
#pragma unroll
  for (int mi = 0; mi < 4; ++mi)
#pragma unroll
    for (int nt = 0; nt < 2; ++nt)
#pragma unroll
      for (int jp = 0; jp < 2; ++jp) { facc[mi][nt][jp][0] = 0.f; facc[mi][nt][jp][1] = 0.f; }

  const int DRt[4] = {0, 1, 1, -1};
  const int DCt[4] = {1, 0, 1, 1};

  __syncthreads();   // xin ready

#pragma clang loop unroll(disable)
  for (int d = 0; d < 4; ++d) {
    const int dr = DRt[d], dc = DCt[d];

    // map conv (K=2, 3 taps) + silu -> bufA
    {
      const int chb = ng*64 + lrow;
#pragma unroll
      for (int mi = 0; mi < 4; ++mi)
#pragma unroll
        for (int nt = 0; nt < 4; ++nt) {
          const int ch = chb + nt*16;
          const float mb = ldp(map_b, ch, isf);
#pragma unroll
          for (int jp = 0; jp < 2; ++jp)
#pragma unroll
            for (int h = 0; h < 2; ++h) {
              const int cell = (mt0 + mi)*16 + quad*4 + jp*2 + h;
              if (cell < NCELL) {
                const int r = cell/15, c = cell - r*15;
                float s = mb;
#pragma unroll
                for (int t = 0; t < 3; ++t) {
                  const int rr = r + (t-1)*dr, cc = c + (t-1)*dc;
                  if (rr >= 0 && rr < 15 && cc >= 0 && cc < 15) {
                    const int sp = rr*15 + cc;
                    s += (float)wbuf[W_MAP + (t*128 + ch)*2 + 0] * xin[sp];
                    s += (float)wbuf[W_MAP + (t*128 + ch)*2 + 1] * xin[225 + sp];
                  }
                }
                bufA[cell*AST + ch] = (f16)silu_f(s);
              }
            }
        }
    }
    __syncthreads();

#pragma clang loop unroll(disable)
    for (int l = 0; l < 4; ++l) {
      phase<3, 0>(bufA, bufB, wbuf + W_DCONV + (size_t)l*3*128*128, dconv_b, (size_t)l*128, isf, dr, dc, tid);
      phase<1, 1>(bufB, bufA, wbuf + W_C1 + (size_t)l*128*128, c1_b, (size_t)l*128, isf, 0, 0, tid);
    }
    phase<1, 0>(bufA, bufB, wbuf + W_R01, r0_b1, 0, isf, 0, 0, tid);
    phase<1, 1>(bufB, bufA, wbuf + W_R02, r0_b2, 0, isf, 0, 0, tid);

    // ---- fin: 64 out-ch, tanh-clamp += facc (reads bufA, no writes) ----
    {
#pragma unroll
      for (int nt = 0; nt < 2; ++nt) {
        const int ch = ng*32 + nt*16 + lrow;
        floatx4 fa[4];
#pragma unroll
        for (int mi = 0; mi < 4; ++mi) { floatx4 z = {0.f,0.f,0.f,0.f}; fa[mi] = z; }
#pragma unroll
        for (int kb = 0; kb < 4; ++kb) {
          f16x8 Bf = *(const f16x8*)(wbuf + W_FIN + (size_t)ch*128 + kb*32 + quad*8);
#pragma unroll
          for (int mi = 0; mi < 4; ++mi) {
            const int mt = mt0 + mi;
            if (mt < 15) {
              const int cell = mt*16 + lrow;
              const bool vld = (cell < NCELL);
              const f16* ap = bufA + (vld ? cell : 0)*AST + quad*8;
              f16x8 a = *(const f16x8*)(ap + kb*32);
              if (!vld) { f16x8 z = {}; a = z; }
              fa[mi] = __builtin_amdgcn_mfma_f32_16x16x32_f16(a, Bf, fa[mi], 0, 0, 0);
            }
          }
        }
        const float fb = ldp(fin_b, ch, isf);
#pragma unroll
        for (int mi = 0; mi < 4; ++mi)
#pragma unroll
          for (int jp = 0; jp < 2; ++jp)
#pragma unroll
            for (int h = 0; h < 2; ++h) {
              const int oc = (mt0 + mi)*16 + quad*4 + jp*2 + h;
              if (oc < NCELL)
                facc[mi][nt][jp][h] += tanh_f((fa[mi][jp*2+h] + fb) * (1.f/MAXF)) * MAXF;
            }
      }
    }
    __syncthreads();   // fin reads of bufA done before next map writes
  }

  float* featf = (float*)bufA;   // 225*64*4 = 57,600 B
  {
#pragma unroll
    for (int nt = 0; nt < 2; ++nt) {
      const int ch = ng*32 + nt*16 + lrow;
      const float aw = ldp(prelu_w, ch, isf);
#pragma unroll
      for (int mi = 0; mi < 4; ++mi)
#pragma unroll
        for (int jp = 0; jp < 2; ++jp)
#pragma unroll
          for (int h = 0; h < 2; ++h) {
            const int cell = (mt0 + mi)*16 + quad*4 + jp*2 + h;
            if (cell < NCELL) {
              float s = facc[mi][nt][jp][h];
              s = (s >= 0.f) ? s : aw*s;
              featf[cell*64 + ch] = s * 0.25f;
            }
          }
    }
  }
  __syncthreads();

  // ---- value head: mean over cells of ch 32..63 ----
  {
    const int ch = tid >> 4, strip = tid & 15;
    float s = 0.f;
    for (int cell = strip; cell < NCELL; cell += 16)
      s += featf[cell*64 + 32 + ch];
    vred[tid] = s;
  }
  __syncthreads();
  if (tid < 32) {
    float s = 0.f;
#pragma unroll
    for (int k = 0; k < 16; ++k) s += vred[tid*16 + k];
    vvA[tid] = fmaxf(s * (1.f/225.f), 0.f);
  }
  __syncthreads();
  if (tid < 32) {
    float s = ldp(vl1_b, tid, isf);
    for (int c2 = 0; c2 < 32; ++c2) s += ldp(vl1_w, tid*32 + c2, isf) * vvA[c2];
    vvB[tid] = fminf(fmaxf(s, 0.f), MAXM);
  }
  __syncthreads();
  if (tid < 32) {
    float s = ldp(vl2_b, tid, isf);
    for (int c2 = 0; c2 < 32; ++c2) s += ldp(vl2_w, tid*32 + c2, isf) * vvB[c2];
    vvA[tid] = fminf(fmaxf(s, 0.f), MAXM);
  }
  __syncthreads();
  if (tid < 3) {
    float s = ldp(vlf_b, tid, isf);
    for (int c2 = 0; c2 < 32; ++c2) s += ldp(vlf_w, tid*32 + c2, isf) * vvA[c2];
    out[b*3 + tid] = s * ldp(vscale, 0, isf);
  }
  __syncthreads();   // value reads of featf[ch32..63] done

  // ---- policy head: depthwise 3x3 on ch 0..31 -> featf[cell][32+ch] ----
  for (int i = tid; i < NCELL*32; i += 512) {
    const int cell = i >> 5, ch = i & 31;
    const int r = cell/15, c = cell - r*15;
    float s = ldp(pdw_b, ch, isf);
#pragma unroll
    for (int kr = 0; kr < 3; ++kr)
#pragma unroll
      for (int kc = 0; kc < 3; ++kc) {
        const int rr = r + kr - 1, cc = c + kc - 1;
        if (rr >= 0 && rr < 15 && cc >= 0 && cc < 15)
          s += ldp(pdw_w, (size_t)ch*9 + kr*3 + kc, isf) * featf[(rr*15 + cc)*64 + ch];
      }
    s = (s >= 0.f) ? s : s * (1.f/16.f);
    s = fminf(fmaxf(s, -MAXF), MAXF);
    featf[cell*64 + 32 + ch] = s;
  }
  __syncthreads();

  const float psc = ldp(pscale, 0, isf);
  for (int cell = tid; cell < NCELL; cell += 512) {
    float s = 0.f;
#pragma unroll
    for (int c2 = 0; c2 < 32; ++c2)
      s += ldp(ppw_w, c2, isf) * featf[cell*64 + 32 + c2];
    s = (s >= 0.f) ? s : s * (1.f/16.f);
    out[1536 + b*NCELL + cell] = s * psc;
  }

  if (badflag && b == 0 && tid == 0) out[0] = 100000.f;
}

extern "C" void kernel_launch(void* const* d_in, const int* in_sizes, int n_in,
                              void* d_out, int out_size, void* d_ws, size_t ws_size,
                              hipStream_t stream)
{
  static const int EXP[25] = {230400, 768, 128, 196608, 512, 65536, 512,
                              16384, 128, 16384, 128, 8192, 64, 64,
                              288, 32, 32, 1024, 32, 1024, 32, 96, 3, 1, 1};
  int bad = (n_in != 25) ? 1 : 0;
  if (!bad) for (int i = 0; i < 25; ++i) if (in_sizes[i] != EXP[i]) bad = 1;
  if (out_size != 116736) bad = 1;

  if (hipFuncSetAttribute(reinterpret_cast<const void*>(k_all),
                          hipFuncAttributeMaxDynamicSharedMemorySize,
                          DYN_LDS) != hipSuccess) bad = 1;

  f16* wbuf = (f16*)d_ws;

  k_prep<<<512, 256, 0, stream>>>(d_in[3], d_in[5], d_in[7], d_in[9],
                                  d_in[11], d_in[1], d_in[0], wbuf);

  k_all<<<512, 512, DYN_LDS, stream>>>(
      d_in[0],  d_in[2],  d_in[4],  d_in[6],  d_in[8],
      d_in[10], d_in[12], d_in[13], d_in[14], d_in[15],
      d_in[16], d_in[17], d_in[18], d_in[19], d_in[20],
      d_in[21], d_in[22], d_in[23], d_in[24],
      wbuf, (float*)d_out, bad);
}

// Round 16
// 1267.551 us; speedup vs baseline: 1.7671x; 1.7671x over previous
//
#include <hip/hip_runtime.h>
#include <math.h>

typedef unsigned short u16;
typedef _Float16 f16;
typedef __attribute__((ext_vector_type(8))) _Float16 f16x8;
typedef __attribute__((ext_vector_type(4))) float floatx4;

#define NCELL 225
#define AST   136              // act stride in halves (272 B)
#define MAXF  31.75f
#define MAXM  (127.0f/((4.0f/16.0f)*3600.0f/256.0f))
#define DYN_LDS (2*NCELL*AST*2)   // 122,400 B: bufA | bufB

// f16 weight buffer layout (element offsets)
#define W_DCONV 0
#define W_C1    196608
#define W_R01   262144
#define W_R02   278528
#define W_FIN   294912
#define W_MAP   303104
#define W_TOT   303872

__device__ __forceinline__ float bfu(unsigned h){ union{unsigned i; float f;} v; v.i=h<<16; return v.f; }
__device__ __forceinline__ float silu_f(float x){ return x/(1.f+__expf(-x)); }
__device__ __forceinline__ float tanh_f(float z){ return 1.f - 2.f/(__expf(2.f*z)+1.f); }
__device__ __forceinline__ float ldp(const void* p, size_t i, int isf){
  return isf ? ((const float*)p)[i] : bfu(((const u16*)p)[i]);
}

__global__ __launch_bounds__(256) void k_prep(
    const void* __restrict__ dconv_w, const void* __restrict__ c1_w,
    const void* __restrict__ r0_w1,  const void* __restrict__ r0_w2,
    const void* __restrict__ fin_w,  const void* __restrict__ map_w,
    const void* __restrict__ x, f16* __restrict__ wbuf)
{
  __shared__ int sflag;
  if (threadIdx.x < 64) {
    unsigned v = ((const u16*)x)[2*threadIdx.x];
    unsigned long long m = __ballot(v > 0x4000u);
    if (threadIdx.x == 0) sflag = (__popcll(m) > 16) ? 1 : 0;
  }
  __syncthreads();
  const int isf = sflag;
  for (int i = blockIdx.x*256 + threadIdx.x; i < W_TOT; i += gridDim.x*256) {
    float v; int j = i;
    if (j < 196608)            v = ldp(dconv_w, j, isf);
    else if ((j -= 196608) < 65536) v = ldp(c1_w, j, isf);
    else if ((j -= 65536) < 16384)  v = ldp(r0_w1, j, isf);
    else if ((j -= 16384) < 16384)  v = ldp(r0_w2, j, isf);
    else if ((j -= 16384) < 8192)   v = ldp(fin_w, j, isf);
    else { j -= 8192;               v = ldp(map_w, j, isf); }
    wbuf[i] = (f16)v;
  }
}

// Ping-pong MFMA GEMM phase: reads S, writes D.
// 16 waves = 4 cell-groups (cg) x 4 channel-groups (ng); 32 out-ch/wave.
// MODE 0: D = silu(acc+b). MODE 1: D = silu(acc+b) + D_old (residual read from D).
// t/kb loops NOT unrolled: blocks scheduler load-hoisting (register spill killer).
template<int NTAPS, int MODE>
__device__ __forceinline__ void phase(
    const f16* __restrict__ S, f16* __restrict__ D, const f16* __restrict__ W,
    const void* __restrict__ Bv, size_t b0, int isf,
    int dr, int dc, int tid)
{
  const int lane = tid & 63, wave = tid >> 6;
  const int cg = wave >> 2, ng = wave & 3;
  const int quad = lane >> 4, lrow = lane & 15;
  const int chb = ng*32 + lrow;
  const int mt0 = cg * 4;

  floatx4 acc[4][2];
#pragma unroll
  for (int mi = 0; mi < 4; ++mi)
#pragma unroll
    for (int nt = 0; nt < 2; ++nt) { floatx4 z = {0.f,0.f,0.f,0.f}; acc[mi][nt] = z; }

#pragma clang loop unroll(disable)
  for (int t = 0; t < NTAPS; ++t) {
    const f16* ap[4]; bool vld[4];
#pragma unroll
    for (int mi = 0; mi < 4; ++mi) {
      const int mt = mt0 + mi;
      const int cell = mt*16 + lrow;
      const int r = cell/15, c = cell - r*15;
      const int off = (NTAPS == 3) ? (t - 1) : 0;
      const int rr = r + off*dr, cc = c + off*dc;
      vld[mi] = (mt < 15) & (cell < NCELL) & (rr >= 0) & (rr < 15) & (cc >= 0) & (cc < 15);
      ap[mi] = S + (vld[mi] ? (rr*15 + cc) : 0)*AST + quad*8;
    }
#pragma clang loop unroll(disable)
    for (int kb = 0; kb < 4; ++kb) {
      f16x8 Bf[2];
#pragma unroll
      for (int nt = 0; nt < 2; ++nt)
        Bf[nt] = *(const f16x8*)(W + (size_t)(t*128 + chb + nt*16)*128 + kb*32 + quad*8);
#pragma unroll
      for (int mi = 0; mi < 4; ++mi) {
        if (mt0 + mi < 15) {
          f16x8 a = *(const f16x8*)(ap[mi] + kb*32);
          if (!vld[mi]) { f16x8 z = {}; a = z; }
#pragma unroll
          for (int nt = 0; nt < 2; ++nt)
            acc[mi][nt] = __builtin_amdgcn_mfma_f32_16x16x32_f16(a, Bf[nt], acc[mi][nt], 0, 0, 0);
        }
      }
    }
  }

  float bn[2];
#pragma unroll
  for (int nt = 0; nt < 2; ++nt) bn[nt] = ldp(Bv, b0 + chb + nt*16, isf);

  // Epilogue: owner-only read-modify-write of D (safe: disjoint positions).
#pragma unroll
  for (int mi = 0; mi < 4; ++mi)
#pragma unroll
    for (int nt = 0; nt < 2; ++nt)
#pragma unroll
      for (int jp = 0; jp < 2; ++jp)
#pragma unroll
        for (int h = 0; h < 2; ++h) {
          const int oc = (mt0 + mi)*16 + quad*4 + jp*2 + h;
          if (oc < NCELL) {
            float v = silu_f(acc[mi][nt][jp*2+h] + bn[nt]);
            if (MODE == 1) v += (float)D[oc*AST + chb + nt*16];
            D[oc*AST + chb + nt*16] = (f16)v;
          }
        }
  __syncthreads();
}

__global__ __launch_bounds__(1024, 4) void k_all(
    const void* __restrict__ x,
    const void* __restrict__ map_b,  const void* __restrict__ dconv_b,
    const void* __restrict__ c1_b,   const void* __restrict__ r0_b1,
    const void* __restrict__ r0_b2,  const void* __restrict__ fin_b,
    const void* __restrict__ prelu_w,
    const void* __restrict__ pdw_w,  const void* __restrict__ pdw_b,
    const void* __restrict__ ppw_w,
    const void* __restrict__ vl1_w,  const void* __restrict__ vl1_b,
    const void* __restrict__ vl2_w,  const void* __restrict__ vl2_b,
    const void* __restrict__ vlf_w,  const void* __restrict__ vlf_b,
    const void* __restrict__ pscale, const void* __restrict__ vscale,
    const f16* __restrict__ wbuf, float* __restrict__ out, int badflag)
{
  extern __shared__ __align__(16) char dyn[];
  f16* bufA = (f16*)dyn;                 // 61,200 B
  f16* bufB = bufA + NCELL*AST;          // 61,200 B
  __shared__ float xin[450];
  __shared__ float vred[1024];
  __shared__ float vvA[32], vvB[32];
  __shared__ int sflag;

  const int b = blockIdx.x, tid = threadIdx.x;
  const int lane = tid & 63, wave = tid >> 6;
  const int cg = wave >> 2, ng = wave & 3;
  const int quad = lane >> 4, lrow = lane & 15;
  const int mt0 = cg * 4;

  if (tid < 64) {
    unsigned v = ((const u16*)x)[2*tid];
    unsigned long long m = __ballot(v > 0x4000u);
    if (tid == 0) sflag = (__popcll(m) > 16) ? 1 : 0;
  }
  __syncthreads();
  const int isf = sflag;

  for (int i = tid; i < 450; i += 1024)
    xin[i] = ldp(x, (size_t)b*450 + i, isf);

  float facc[4][2][2];     // fin accumulator: [mi][jp][h], ch = ng*16+lrow
#pragma unroll
  for (int mi = 0; mi < 4; ++mi)
#pragma unroll
    for (int jp = 0; jp < 2; ++jp) { facc[mi][jp][0] = 0.f; facc[mi][jp][1] = 0.f; }

  const int DRt[4] = {0, 1, 1, -1};
  const int DCt[4] = {1, 0, 1, 1};

  __syncthreads();   // xin ready

#pragma clang loop unroll(disable)
  for (int d = 0; d < 4; ++d) {
    const int dr = DRt[d], dc = DCt[d];

    // map conv (K=2, 3 taps) + silu -> bufA
    {
      const int chb = ng*32 + lrow;
#pragma unroll
      for (int mi = 0; mi < 4; ++mi)
#pragma unroll
        for (int nt = 0; nt < 2; ++nt) {
          const int ch = chb + nt*16;
          const float mb = ldp(map_b, ch, isf);
#pragma unroll
          for (int jp = 0; jp < 2; ++jp)
#pragma unroll
            for (int h = 0; h < 2; ++h) {
              const int cell = (mt0 + mi)*16 + quad*4 + jp*2 + h;
              if (cell < NCELL) {
                const int r = cell/15, c = cell - r*15;
                float s = mb;
#pragma unroll
                for (int t = 0; t < 3; ++t) {
                  const int rr = r + (t-1)*dr, cc = c + (t-1)*dc;
                  if (rr >= 0 && rr < 15 && cc >= 0 && cc < 15) {
                    const int sp = rr*15 + cc;
                    s += (float)wbuf[W_MAP + (t*128 + ch)*2 + 0] * xin[sp];
                    s += (float)wbuf[W_MAP + (t*128 + ch)*2 + 1] * xin[225 + sp];
                  }
                }
                bufA[cell*AST + ch] = (f16)silu_f(s);
              }
            }
        }
    }
    __syncthreads();

#pragma clang loop unroll(disable)
    for (int l = 0; l < 4; ++l) {
      phase<3, 0>(bufA, bufB, wbuf + W_DCONV + (size_t)l*3*128*128, dconv_b, (size_t)l*128, isf, dr, dc, tid);
      phase<1, 1>(bufB, bufA, wbuf + W_C1 + (size_t)l*128*128, c1_b, (size_t)l*128, isf, 0, 0, tid);
    }
    phase<1, 0>(bufA, bufB, wbuf + W_R01, r0_b1, 0, isf, 0, 0, tid);
    phase<1, 1>(bufB, bufA, wbuf + W_R02, r0_b2, 0, isf, 0, 0, tid);

    // ---- fin: 64 out-ch, tanh-clamp += facc (reads bufA, no writes) ----
    {
      const int ch = ng*16 + lrow;
      floatx4 fa[4];
#pragma unroll
      for (int mi = 0; mi < 4; ++mi) { floatx4 z = {0.f,0.f,0.f,0.f}; fa[mi] = z; }
#pragma clang loop unroll(disable)
      for (int kb = 0; kb < 4; ++kb) {
        f16x8 Bf = *(const f16x8*)(wbuf + W_FIN + (size_t)ch*128 + kb*32 + quad*8);
#pragma unroll
        for (int mi = 0; mi < 4; ++mi) {
          const int mt = mt0 + mi;
          if (mt < 15) {
            const int cell = mt*16 + lrow;
            const bool vld = (cell < NCELL);
            const f16* ap = bufA + (vld ? cell : 0)*AST + quad*8;
            f16x8 a = *(const f16x8*)(ap + kb*32);
            if (!vld) { f16x8 z = {}; a = z; }
            fa[mi] = __builtin_amdgcn_mfma_f32_16x16x32_f16(a, Bf, fa[mi], 0, 0, 0);
          }
        }
      }
      const float fb = ldp(fin_b, ch, isf);
#pragma unroll
      for (int mi = 0; mi < 4; ++mi)
#pragma unroll
        for (int jp = 0; jp < 2; ++jp)
#pragma unroll
          for (int h = 0; h < 2; ++h) {
            const int oc = (mt0 + mi)*16 + quad*4 + jp*2 + h;
            if (oc < NCELL)
              facc[mi][jp][h] += tanh_f((fa[mi][jp*2+h] + fb) * (1.f/MAXF)) * MAXF;
          }
    }
    __syncthreads();   // fin reads of bufA done before next map writes
  }

  float* featf = (float*)bufA;   // 225*64*4 = 57,600 B
  {
    const int ch = ng*16 + lrow;
    const float aw = ldp(prelu_w, ch, isf);
#pragma unroll
    for (int mi = 0; mi < 4; ++mi)
#pragma unroll
      for (int jp = 0; jp < 2; ++jp)
#pragma unroll
        for (int h = 0; h < 2; ++h) {
          const int cell = (mt0 + mi)*16 + quad*4 + jp*2 + h;
          if (cell < NCELL) {
            float s = facc[mi][jp][h];
            s = (s >= 0.f) ? s : aw*s;
            featf[cell*64 + ch] = s * 0.25f;
          }
        }
  }
  __syncthreads();

  // ---- value head: mean over cells of ch 32..63 ----
  {
    const int ch = tid >> 5, strip = tid & 31;
    float s = 0.f;
    for (int cell = strip; cell < NCELL; cell += 32)
      s += featf[cell*64 + 32 + ch];
    vred[tid] = s;
  }
  __syncthreads();
  if (tid < 32) {
    float s = 0.f;
#pragma unroll
    for (int k = 0; k < 32; ++k) s += vred[tid*32 + k];
    vvA[tid] = fmaxf(s * (1.f/225.f), 0.f);
  }
  __syncthreads();
  if (tid < 32) {
    float s = ldp(vl1_b, tid, isf);
    for (int c2 = 0; c2 < 32; ++c2) s += ldp(vl1_w, tid*32 + c2, isf) * vvA[c2];
    vvB[tid] = fminf(fmaxf(s, 0.f), MAXM);
  }
  __syncthreads();
  if (tid < 32) {
    float s = ldp(vl2_b, tid, isf);
    for (int c2 = 0; c2 < 32; ++c2) s += ldp(vl2_w, tid*32 + c2, isf) * vvB[c2];
    vvA[tid] = fminf(fmaxf(s, 0.f), MAXM);
  }
  __syncthreads();
  if (tid < 3) {
    float s = ldp(vlf_b, tid, isf);
    for (int c2 = 0; c2 < 32; ++c2) s += ldp(vlf_w, tid*32 + c2, isf) * vvA[c2];
    out[b*3 + tid] = s * ldp(vscale, 0, isf);
  }
  __syncthreads();   // value reads of featf[ch32..63] done

  // ---- policy head: depthwise 3x3 on ch 0..31 -> featf[cell][32+ch] ----
  for (int i = tid; i < NCELL*32; i += 1024) {
    const int cell = i >> 5, ch = i & 31;
    const int r = cell/15, c = cell - r*15;
    float s = ldp(pdw_b, ch, isf);
#pragma unroll
    for (int kr = 0; kr < 3; ++kr)
#pragma unroll
      for (int kc = 0; kc < 3; ++kc) {
        const int rr = r + kr - 1, cc = c + kc - 1;
        if (rr >= 0 && rr < 15 && cc >= 0 && cc < 15)
          s += ldp(pdw_w, (size_t)ch*9 + kr*3 + kc, isf) * featf[(rr*15 + cc)*64 + ch];
      }
    s = (s >= 0.f) ? s : s * (1.f/16.f);
    s = fminf(fmaxf(s, -MAXF), MAXF);
    featf[cell*64 + 32 + ch] = s;
  }
  __syncthreads();

  const float psc = ldp(pscale, 0, isf);
  for (int cell = tid; cell < NCELL; cell += 1024) {
    float s = 0.f;
#pragma unroll
    for (int c2 = 0; c2 < 32; ++c2)
      s += ldp(ppw_w, c2, isf) * featf[cell*64 + 32 + c2];
    s = (s >= 0.f) ? s : s * (1.f/16.f);
    out[1536 + b*NCELL + cell] = s * psc;
  }

  if (badflag && b == 0 && tid == 0) out[0] = 100000.f;
}

extern "C" void kernel_launch(void* const* d_in, const int* in_sizes, int n_in,
                              void* d_out, int out_size, void* d_ws, size_t ws_size,
                              hipStream_t stream)
{
  static const int EXP[25] = {230400, 768, 128, 196608, 512, 65536, 512,
                              16384, 128, 16384, 128, 8192, 64, 64,
                              288, 32, 32, 1024, 32, 1024, 32, 96, 3, 1, 1};
  int bad = (n_in != 25) ? 1 : 0;
  if (!bad) for (int i = 0; i < 25; ++i) if (in_sizes[i] != EXP[i]) bad = 1;
  if (out_size != 116736) bad = 1;

  if (hipFuncSetAttribute(reinterpret_cast<const void*>(k_all),
                          hipFuncAttributeMaxDynamicSharedMemorySize,
                          DYN_LDS) != hipSuccess) bad = 1;

  f16* wbuf = (f16*)d_ws;

  k_prep<<<512, 256, 0, stream>>>(d_in[3], d_in[5], d_in[7], d_in[9],
                                  d_in[11], d_in[1], d_in[0], wbuf);

  k_all<<<512, 1024, DYN_LDS, stream>>>(
      d_in[0],  d_in[2],  d_in[4],  d_in[6],  d_in[8],
      d_in[10], d_in[12], d_in[13], d_in[14], d_in[15],
      d_in[16], d_in[17], d_in[18], d_in[19], d_in[20],
      d_in[21], d_in[22], d_in[23], d_in[24],
      wbuf, (float*)d_out, bad);
}